// Round 4
// baseline (1628.439 us; speedup 1.0000x reference)
//
#include <hip/hip_runtime.h>
#include <stdint.h>

// ---------------- types ----------------
typedef __attribute__((ext_vector_type(8))) short short8;   // 8 x bf16 (4 VGPR) MFMA A/B frag
typedef __attribute__((ext_vector_type(4))) short short4v;  // 8B packed LDS write
typedef __attribute__((ext_vector_type(4))) float float4v;  // MFMA C/D frag

__device__ __forceinline__ short f2bf(float f) {
  uint32_t u = __builtin_bit_cast(uint32_t, f);
  u += 0x7FFFu + ((u >> 16) & 1u);   // round-to-nearest-even
  return (short)(u >> 16);
}

// =====================================================================
// LDS swizzle scheme (row-major short buffers, 16B-unit XOR):
//   element (row, k) stored at row*RS + (k ^ ((row&7)<<3))   [k in shorts]
// b128 reads use two per-lane bases (even/odd 32-short granule):
//   offE = ((quad ^ (r&3))<<3) | ((r>>2)<<5),  offO = offE ^ 32,  r = l16&7
// (also valid for RS=256: the XOR only touches bits 3-5 of the k index)
// =====================================================================

// =====================================================================
// Kernel 1: convert weights to bf16 in workspace
// =====================================================================
__global__ void prep_weights(const float* __restrict__ wq, const float* __restrict__ wp,
                             short* __restrict__ wq_b, short* __restrict__ wp_b) {
  int i = blockIdx.x * blockDim.x + threadIdx.x;
  int stride = gridDim.x * blockDim.x;
  for (int j = i; j < 786432 / 4; j += stride) {
    float4 v = ((const float4*)wq)[j];
    short4v t = {f2bf(v.x), f2bf(v.y), f2bf(v.z), f2bf(v.w)};
    ((short4v*)wq_b)[j] = t;
  }
  for (int j = i; j < 262144 / 4; j += stride) {
    float4 v = ((const float4*)wp)[j];
    short4v t = {f2bf(v.x), f2bf(v.y), f2bf(v.z), f2bf(v.w)};
    ((short4v*)wp_b)[j] = t;
  }
}

// =====================================================================
// Kernel 2: FULLY FUSED qkv-GEMM + window attention + output projection.
// Eliminates the 128MB attn HBM round-trip and the proj_gemm dispatch.
// 512 persistent blocks x 4 windows; 1024 threads = 16 waves.
// Per window (out accum pacc[8] f32x4 persists across rounds, K=512 total):
//   round h0 in {0,4} (4 heads each):
//     phase1: merged {Qt,Kt,V} strip triple per wave, 3-deep W prefetch.
//     sync
//     phase2a: S=Q*K^T + analytic bias + shfl softmax       (last Ks read)
//     sync
//     phase2b: P->Qs (wave-local), O=P*Vt, O -> Os (ALIASES Ks -- dead now)
//     sync
//     proj partial: pacc += Os(64x256) @ wp[:, h0*64..h0*64+256)^T
//                   (wp rows streamed from L2, Os A-frags from LDS)
//     sync
//   epilogue: out[b] = pacc + bproj  (fp32, full 64B-line stores)
// LDS: Xs 64K + Qs 32K + Ks/Os 32K + Vt 32K = 163,840 B. XOR-swizzled.
// =====================================================================
__global__ __launch_bounds__(1024, 4)
void qkv_attn_proj(const float* __restrict__ x, const short* __restrict__ wq,
                   const float* __restrict__ bqkv, const float* __restrict__ btab,
                   const short* __restrict__ wp, const float* __restrict__ bproj,
                   float* __restrict__ out) {
  __shared__ short Xs[64 * 512];        // 65,536 B
  __shared__ short Qs[4][64 * 64];      // 32,768 B
  __shared__ short Ks[4][64 * 64];      // 32,768 B  (aliased as Os[64][256] in proj)
  __shared__ short Vt[4][64 * 64];      // 32,768 B   total 163,840 B

  short* Os = &Ks[0][0];                // alias: Os[row][c] at row*256 + swz(c)

  const int blk  = blockIdx.x;     // 0..511
  const int tid  = threadIdx.x;
  const int lane = tid & 63;
  const int w    = tid >> 6;       // wave 0..15
  const int l16  = lane & 15;
  const int quad = lane >> 4;      // 0..3
  const int r    = l16 & 7;
  const int offE = ((quad ^ (r & 3)) << 3) | ((r >> 2) << 5);
  const int offO = offE ^ 32;

  const int g  = w >> 2;   // head offset within round (Q,V) ; K head = g^1
  const int st = w & 3;    // 16-row strip
  // proj decomposition: wave -> (row strip cs, col group cg)
  const int cs = w & 3;    // out rows cs*16..+16
  const int cg = w >> 2;   // out cols cg*128..+128

  // proj bias frags (window-invariant)
  float bj[8];
#pragma unroll
  for (int tj = 0; tj < 8; ++tj) bj[tj] = bproj[cg * 128 + tj * 16 + l16];

#pragma unroll 1
  for (int vi = 0; vi < 4; ++vi) {
    const int b   = blk * 4 + vi;
    const int lat = b >> 6;          // MLON = 64

    float4v pacc[8] = {};            // out[cs*16..+16][cg*128..+128], both rounds

    // ---- stage X window into LDS as bf16 (swizzled write) ----
    const float* xw = x + (size_t)b * (64 * 512);
    for (int c = tid; c < 64 * 128; c += 1024) {   // float4 chunks
      int n = c >> 7, kc = c & 127;
      float4 v = *(const float4*)(xw + n * 512 + kc * 4);
      short4v t = {f2bf(v.x), f2bf(v.y), f2bf(v.z), f2bf(v.w)};
      *(short4v*)&Xs[n * 512 + ((kc * 4) ^ ((n & 7) << 3))] = t;
    }
    __syncthreads();

#pragma unroll 1
    for (int h0 = 0; h0 < 8; h0 += 4) {
      // ---------------- phase 1: QKV GEMMs (strip-merged, prefetched) ----------------
      {
        const int hq = h0 + g;
        const int hk = h0 + (g ^ 1);
        const short* Aq = wq + (size_t)((hq * 64 + st * 16 + l16) * 512) + quad * 8;
        const short* Ak = wq + (size_t)((512 + hk * 64 + st * 16 + l16) * 512) + quad * 8;
        const short* Av = wq + (size_t)((1024 + hq * 64 + st * 16 + l16) * 512) + quad * 8;
        const short* xE = &Xs[l16 * 512 + offE];
        const short* xO = &Xs[l16 * 512 + offO];

        short8 wqp[3], wkp[3], wvp[3];
        wqp[0] = *(const short8*)(Aq);      wqp[1] = *(const short8*)(Aq + 32);
        wkp[0] = *(const short8*)(Ak);      wkp[1] = *(const short8*)(Ak + 32);
        wvp[0] = *(const short8*)(Av);      wvp[1] = *(const short8*)(Av + 32);

        float4v aQ[4] = {}, aK[4] = {}, aV[4] = {};
#pragma unroll
        for (int j = 0; j < 16; ++j) {            // kk = j*32
          if (j + 2 < 16) {
            wqp[(j + 2) % 3] = *(const short8*)(Aq + (j + 2) * 32);
            wkp[(j + 2) % 3] = *(const short8*)(Ak + (j + 2) * 32);
            wvp[(j + 2) % 3] = *(const short8*)(Av + (j + 2) * 32);
          }
          const short* xb = (j & 1) ? xO : xE;
          const int xoff = (j >> 1) * 64;
          short8 x0 = *(const short8*)(xb + xoff);
          short8 x1 = *(const short8*)(xb + 8192 + xoff);
          short8 x2 = *(const short8*)(xb + 16384 + xoff);
          short8 x3 = *(const short8*)(xb + 24576 + xoff);
          short8 Wq = wqp[j % 3], Wk = wkp[j % 3], Wv = wvp[j % 3];
          aQ[0] = __builtin_amdgcn_mfma_f32_16x16x32_bf16(Wq, x0, aQ[0], 0, 0, 0);
          aQ[1] = __builtin_amdgcn_mfma_f32_16x16x32_bf16(Wq, x1, aQ[1], 0, 0, 0);
          aQ[2] = __builtin_amdgcn_mfma_f32_16x16x32_bf16(Wq, x2, aQ[2], 0, 0, 0);
          aQ[3] = __builtin_amdgcn_mfma_f32_16x16x32_bf16(Wq, x3, aQ[3], 0, 0, 0);
          aK[0] = __builtin_amdgcn_mfma_f32_16x16x32_bf16(Wk, x0, aK[0], 0, 0, 0);
          aK[1] = __builtin_amdgcn_mfma_f32_16x16x32_bf16(Wk, x1, aK[1], 0, 0, 0);
          aK[2] = __builtin_amdgcn_mfma_f32_16x16x32_bf16(Wk, x2, aK[2], 0, 0, 0);
          aK[3] = __builtin_amdgcn_mfma_f32_16x16x32_bf16(Wk, x3, aK[3], 0, 0, 0);
          aV[0] = __builtin_amdgcn_mfma_f32_16x16x32_bf16(x0, Wv, aV[0], 0, 0, 0);
          aV[1] = __builtin_amdgcn_mfma_f32_16x16x32_bf16(x1, Wv, aV[1], 0, 0, 0);
          aV[2] = __builtin_amdgcn_mfma_f32_16x16x32_bf16(x2, Wv, aV[2], 0, 0, 0);
          aV[3] = __builtin_amdgcn_mfma_f32_16x16x32_bf16(x3, Wv, aV[3], 0, 0, 0);
        }

        // ---- epilogues (identical math; swizzled LDS writes) ----
        float bq[4], bk[4];
#pragma unroll
        for (int i = 0; i < 4; ++i) {
          bq[i] = bqkv[hq * 64 + st * 16 + quad * 4 + i];
          bk[i] = bqkv[512 + hk * 64 + st * 16 + quad * 4 + i];
        }
        short* dq = &Qs[g][0];
        short* dk = &Ks[g ^ 1][0];
        const int swqk = (st * 16 + quad * 4) ^ (r << 3);   // rows t*16+l16 have row&7==r
#pragma unroll
        for (int t = 0; t < 4; ++t) {
          int n = t * 16 + l16;
          short4v pq, pk;
#pragma unroll
          for (int i = 0; i < 4; ++i) {
            pq[i] = f2bf((aQ[t][i] + bq[i]) * 0.125f);   // fold q-scale (exact pow2)
            pk[i] = f2bf(aK[t][i] + bk[i]);
          }
          *(short4v*)&dq[n * 64 + swqk] = pq;  // [n][d] packed, swizzled
          *(short4v*)&dk[n * 64 + swqk] = pk;
        }
        float bv = bqkv[1024 + hq * 64 + st * 16 + l16];
        const int dv = st * 16 + l16;          // Vt row (= d); dv&7 == r
#pragma unroll
        for (int t = 0; t < 4; ++t) {
          short4v pv;
#pragma unroll
          for (int i = 0; i < 4; ++i) pv[i] = f2bf(aV[t][i] + bv);
          *(short4v*)&Vt[g][dv * 64 + ((t * 16 + quad * 4) ^ (r << 3))] = pv;  // [d][m]
        }
      }
      __syncthreads();

      // ---------------- phase 2a: S = Q*K^T + bias + softmax ----------------
      const int hsel = w >> 2;
      const int h    = h0 + hsel;
      const int n0   = (w & 3) * 16;
      const short* Qb = &Qs[hsel][0];
      const short* Kb = &Ks[hsel][0];
      const short* Vb = &Vt[hsel][0];

      float p[4][4];
      {
        float4v s4[4] = {};
#pragma unroll
        for (int j = 0; j < 2; ++j) {
          const int o = j ? offO : offE;
          short8 a = *(const short8*)&Qb[(n0 + l16) * 64 + o];
#pragma unroll
          for (int t = 0; t < 4; ++t) {
            short8 bf = *(const short8*)&Kb[(t * 16 + l16) * 64 + o];
            s4[t] = __builtin_amdgcn_mfma_f32_16x16x32_bf16(a, bf, s4[t], 0, 0, 0);
          }
        }
        // analytic earth bias (skips rel_idx input entirely)
#pragma unroll
        for (int t = 0; t < 4; ++t) {
          int m = t * 16 + l16;
#pragma unroll
          for (int i = 0; i < 4; ++i) {
            int n = n0 + quad * 4 + i;
            int idx = ((n >> 3) - (m >> 3) + 7) * 15 + ((n & 7) - (m & 7) + 7) + lat * 225;
            s4[t][i] += btab[idx * 8 + h];
          }
        }
        // row softmax: row n held at fixed reg i across 16 lanes of the quad
#pragma unroll
        for (int i = 0; i < 4; ++i) {
          float mx = fmaxf(fmaxf(s4[0][i], s4[1][i]), fmaxf(s4[2][i], s4[3][i]));
          mx = fmaxf(mx, __shfl_xor(mx, 1));
          mx = fmaxf(mx, __shfl_xor(mx, 2));
          mx = fmaxf(mx, __shfl_xor(mx, 4));
          mx = fmaxf(mx, __shfl_xor(mx, 8));
          float e0 = __expf(s4[0][i] - mx), e1 = __expf(s4[1][i] - mx);
          float e2 = __expf(s4[2][i] - mx), e3 = __expf(s4[3][i] - mx);
          float sm = e0 + e1 + e2 + e3;
          sm += __shfl_xor(sm, 1);
          sm += __shfl_xor(sm, 2);
          sm += __shfl_xor(sm, 4);
          sm += __shfl_xor(sm, 8);
          float inv = 1.0f / sm;
          p[0][i] = e0 * inv; p[1][i] = e1 * inv; p[2][i] = e2 * inv; p[3][i] = e3 * inv;
        }
      }
      __syncthreads();   // ALL Ks reads done -> Os may overwrite Ks region

      // ---------------- phase 2b: P->LDS, O=P*V, O->Os ----------------
      {
        // P -> own Q rows (wave-local round trip)
        short* Pw = &Qs[hsel][0];
#pragma unroll
        for (int t = 0; t < 4; ++t)
#pragma unroll
          for (int i = 0; i < 4; ++i) {
            int row = n0 + quad * 4 + i;
            Pw[row * 64 + ((t * 16 + l16) ^ ((row & 7) << 3))] = f2bf(p[t][i]);
          }

        float4v o4[4] = {};
#pragma unroll
        for (int j = 0; j < 2; ++j) {
          const int o = j ? offO : offE;
          short8 a = *(const short8*)&Qb[(n0 + l16) * 64 + o];
#pragma unroll
          for (int t = 0; t < 4; ++t) {
            short8 bf = *(const short8*)&Vb[(t * 16 + l16) * 64 + o];
            o4[t] = __builtin_amdgcn_mfma_f32_16x16x32_bf16(a, bf, o4[t], 0, 0, 0);
          }
        }
        // O -> Os[64][256] (over Ks): element (row, c=hsel*64+t*16+l16)
#pragma unroll
        for (int t = 0; t < 4; ++t)
#pragma unroll
          for (int i = 0; i < 4; ++i) {
            int row = n0 + quad * 4 + i;
            Os[row * 256 + hsel * 64 + ((t * 16 + l16) ^ ((row & 7) << 3))] = f2bf(o4[t][i]);
          }
      }
      __syncthreads();   // Os complete

      // ---------------- proj partial: pacc += Os @ wp[:, kbase..+256)^T ----------------
      {
        const int kbase = h0 * 64;   // 0 or 256
        const short* OsA = Os + (cs * 16 + l16) * 256;
        const short* wpb = wp + (size_t)(cg * 128 + l16) * 512 + kbase + quad * 8;
#pragma unroll
        for (int ks = 0; ks < 8; ++ks) {
          short8 a = *(const short8*)(OsA + (ks >> 1) * 64 + ((ks & 1) ? offO : offE));
          short8 wf[4];
#pragma unroll
          for (int tj = 0; tj < 4; ++tj)
            wf[tj] = *(const short8*)(wpb + tj * 8192 + ks * 32);
#pragma unroll
          for (int tj = 0; tj < 4; ++tj)
            pacc[tj] = __builtin_amdgcn_mfma_f32_16x16x32_bf16(a, wf[tj], pacc[tj], 0, 0, 0);
#pragma unroll
          for (int tj = 0; tj < 4; ++tj)
            wf[tj] = *(const short8*)(wpb + (tj + 4) * 8192 + ks * 32);
#pragma unroll
          for (int tj = 0; tj < 4; ++tj)
            pacc[tj + 4] = __builtin_amdgcn_mfma_f32_16x16x32_bf16(a, wf[tj], pacc[tj + 4], 0, 0, 0);
        }
      }
      __syncthreads();   // before next round's phase1 overwrites Qs/Ks/Vt
    }

    // ---------------- epilogue: out[b] = pacc + bproj (fp32) ----------------
    {
      float* ob = out + (size_t)b * (64 * 512);
#pragma unroll
      for (int tj = 0; tj < 8; ++tj)
#pragma unroll
        for (int i = 0; i < 4; ++i)
          ob[(size_t)(cs * 16 + quad * 4 + i) * 512 + cg * 128 + tj * 16 + l16] =
              pacc[tj][i] + bj[tj];
    }
    // no barrier needed: next vi's Xs staging conflicts only with phase-1
    // reads, which completed before this round's final __syncthreads().
  }
}

// =====================================================================
extern "C" void kernel_launch(void* const* d_in, const int* in_sizes, int n_in,
                              void* d_out, int out_size, void* d_ws, size_t ws_size,
                              hipStream_t stream) {
  const float* x     = (const float*)d_in[0];   // (2048, 64, 512)
  const float* wqkv  = (const float*)d_in[1];   // (1536, 512)
  const float* bqkv  = (const float*)d_in[2];   // (1536,)
  const float* wproj = (const float*)d_in[3];   // (512, 512)
  const float* bproj = (const float*)d_in[4];   // (512,)
  const float* btab  = (const float*)d_in[5];   // (7200, 8)
  // d_in[6] = rel_idx -- recomputed analytically in-kernel, not read.
  float* out = (float*)d_out;

  short* wq_b = (short*)d_ws;            // 786,432 bf16
  short* wp_b = wq_b + 786432;           // 262,144 bf16

  prep_weights<<<256, 256, 0, stream>>>(wqkv, wproj, wq_b, wp_b);
  qkv_attn_proj<<<512, 1024, 0, stream>>>(x, wq_b, bqkv, btab, wp_b, bproj, out);
}